// Round 5
// baseline (2570.376 us; speedup 1.0000x reference)
//
#include <hip/hip_runtime.h>
#include <math.h>

// H[i,j] = max_k ( |W[i,k]| + |W[j,k]| ), W: 2048 x 10000 fp32 (values >= 0).
// Max-plus gram: pure VALU (no MFMA). Round 5: round-4 structure, but
//  (a) SPLIT 4 -> 10: 1360 blocks = 5.3 blocks/CU = 5 waves/SIMD (round 4's
//      2.1 waves/SIMD left the VALU at ~36% duty, latency-bound on ds_read;
//      VALUBusy is a CU-OR metric and hid this),
//  (b) canonical-orientation atomics only + separate LDS-tiled mirror kernel
//      (halves hot-kernel atomic traffic vs writing both orientations).
// KS=1000 keeps every split's float4 base 16B-aligned. Step overlap past a
// split's end is harmless for max; kg<K guards the global end.

constexpr int N  = 2048;
constexpr int K  = 10000;
constexpr int BT = 128;                  // output tile dim
constexpr int BK = 32;                   // k per step
constexpr int NT = N / BT;               // 16
constexpr int NTRI = NT * (NT + 1) / 2;  // 136 upper-tri tiles
constexpr int SPLIT = 10;                // K-split across blocks
constexpr int KS = 1000;                 // per-split k span (mult of 4!)
constexpr int NSTEP = 32;                // 32*32=1024 >= 1000 (overlap ok)

__device__ __forceinline__ float max3f(float a, float b, float c) {
    float d;
    asm("v_max3_f32 %0, %1, %2, %3" : "=v"(d) : "v"(a), "v"(b), "v"(c));
    return d;
}

__global__ void zero_out_kernel(float4* __restrict__ p, int n4) {
    const int i = blockIdx.x * blockDim.x + threadIdx.x;
    if (i < n4) p[i] = make_float4(0.f, 0.f, 0.f, 0.f);
}

__global__ __launch_bounds__(256, 5)
void tropical_gram_kernel(const float* __restrict__ W, float* __restrict__ H) {
    __shared__ float As[BK][BT];   // k-major: As[k][row]
    __shared__ float Bs[BK][BT];

    const int tid = threadIdx.x;

    // ---- block decode: split + upper-tri tile (bi <= bj)
    const int bid   = blockIdx.x;
    const int split = bid / NTRI;
    int t = bid % NTRI;
    int bi = 0;
    while (t >= NT - bi) { t -= NT - bi; ++bi; }
    const int bj = bi + t;
    const int i0 = bi * BT, j0 = bj * BT;
    const int kbeg = split * KS;         // multiple of 4 -> float4 aligned
    const bool diag = (bi == bj);

    // ---- staging mapping: thread stages 16 consecutive k of one row/side
    const int srow = tid & 127;          // row within tile
    const int kh   = tid >> 7;           // 0/1: which 16-k half (wave-uniform)
    const float* rowi = W + (size_t)(i0 + srow) * K + kbeg + kh * 16;
    const float* rowj = W + (size_t)(j0 + srow) * K + kbeg + kh * 16;

    // ---- compute mapping: four 4x4 sub-tiles per thread at (+0,+64)
    const int tx = tid & 15, ty = tid >> 4;
    const int ra = ty * 4, rb = ra + 64;   // row starts
    const int ca = tx * 4, cb = ca + 64;   // col starts

    float acc[8][8];   // m: 0-3 -> ra+m, 4-7 -> rb+(m-4); n likewise ca/cb
#pragma unroll
    for (int m = 0; m < 8; ++m)
#pragma unroll
        for (int n = 0; n < 8; ++n) acc[m][n] = 0.0f;  // all sums >= 0

    // ---- prefetch registers (issue early, LDS-write late)
    float4 va[4], vb[4];
    const float4 z4 = make_float4(0.f, 0.f, 0.f, 0.f);

    auto fetchA = [&](int s) {
#pragma unroll
        for (int q = 0; q < 4; ++q) {
            const int kg = kbeg + kh * 16 + s * BK + q * 4;  // global k
            va[q] = (kg < K) ? *reinterpret_cast<const float4*>(rowi + s * BK + q * 4) : z4;
        }
    };
    auto fetchB = [&](int s) {
#pragma unroll
        for (int q = 0; q < 4; ++q) {
            const int kg = kbeg + kh * 16 + s * BK + q * 4;
            vb[q] = (kg < K) ? *reinterpret_cast<const float4*>(rowj + s * BK + q * 4) : z4;
        }
    };

    fetchA(0);
    if (!diag) fetchB(0);

    // diagonal blocks read B fragments from As (half the staging)
    const float (*Bsrc)[BT] = diag ? As : Bs;

    for (int s = 0; s < NSTEP; ++s) {
        __syncthreads();                 // previous compute done with LDS
        // transposed LDS write: bank = srow%32 across lanes -> 2-way (free)
#pragma unroll
        for (int q = 0; q < 4; ++q) {
            const int kb = kh * 16 + q * 4;
            As[kb + 0][srow] = fabsf(va[q].x);
            As[kb + 1][srow] = fabsf(va[q].y);
            As[kb + 2][srow] = fabsf(va[q].z);
            As[kb + 3][srow] = fabsf(va[q].w);
        }
        if (!diag) {
#pragma unroll
            for (int q = 0; q < 4; ++q) {
                const int kb = kh * 16 + q * 4;
                Bs[kb + 0][srow] = fabsf(vb[q].x);
                Bs[kb + 1][srow] = fabsf(vb[q].y);
                Bs[kb + 2][srow] = fabsf(vb[q].z);
                Bs[kb + 3][srow] = fabsf(vb[q].w);
            }
        }
        if (s + 1 < NSTEP) {             // issue next-step loads under compute
            fetchA(s + 1);
            if (!diag) fetchB(s + 1);
        }
        __syncthreads();                 // LDS tile ready

#pragma unroll 2
        for (int kk = 0; kk < BK; kk += 2) {
            // all reads stride-16B across lanes -> <=2-way bank aliasing
            const float4 A0a = *reinterpret_cast<const float4*>(&As[kk][ra]);
            const float4 A0b = *reinterpret_cast<const float4*>(&As[kk][rb]);
            const float4 A1a = *reinterpret_cast<const float4*>(&As[kk + 1][ra]);
            const float4 A1b = *reinterpret_cast<const float4*>(&As[kk + 1][rb]);
            const float4 B0a = *reinterpret_cast<const float4*>(&Bsrc[kk][ca]);
            const float4 B0b = *reinterpret_cast<const float4*>(&Bsrc[kk][cb]);
            const float4 B1a = *reinterpret_cast<const float4*>(&Bsrc[kk + 1][ca]);
            const float4 B1b = *reinterpret_cast<const float4*>(&Bsrc[kk + 1][cb]);
            const float a0[8] = {A0a.x, A0a.y, A0a.z, A0a.w, A0b.x, A0b.y, A0b.z, A0b.w};
            const float a1[8] = {A1a.x, A1a.y, A1a.z, A1a.w, A1b.x, A1b.y, A1b.z, A1b.w};
            const float b0[8] = {B0a.x, B0a.y, B0a.z, B0a.w, B0b.x, B0b.y, B0b.z, B0b.w};
            const float b1[8] = {B1a.x, B1a.y, B1a.z, B1a.w, B1b.x, B1b.y, B1b.z, B1b.w};
#pragma unroll
            for (int m = 0; m < 8; ++m) {
#pragma unroll
                for (int n = 0; n < 8; ++n) {
                    const float t0 = a0[m] + b0[n];
                    const float t1 = a1[m] + b1[n];
                    acc[m][n] = max3f(acc[m][n], t0, t1);
                }
            }
        }
    }

    // ---- epilogue: canonical orientation only; int-bitcast atomicMax merges
    // the K-splits (all values >= 0 -> float order == int order)
    int* Hi = (int*)H;
#pragma unroll
    for (int m = 0; m < 8; ++m) {
        const int r = (m < 4) ? (ra + m) : (rb + m - 4);
#pragma unroll
        for (int n = 0; n < 8; ++n) {
            const int c = (n < 4) ? (ca + n) : (cb + n - 4);
            atomicMax(&Hi[(size_t)(i0 + r) * N + j0 + c], __float_as_int(acc[m][n]));
        }
    }
}

// fill strictly-lower 64-tiles from the upper triangle (H[j][i] = H[i][j]).
// diag-128 tiles were written fully by the gram kernel; re-copying the
// intra-diagonal 64-tile pairs is idempotent (same values).
constexpr int MT  = 64;
constexpr int NT64 = N / MT;                       // 32
constexpr int NMIR = NT64 * (NT64 - 1) / 2;        // 496 strict pairs

__global__ __launch_bounds__(256)
void mirror_kernel(float* __restrict__ H) {
    __shared__ float S[MT][MT + 1];                // +1 pad: conflict-free transpose
    int t = blockIdx.x;
    int ti = 0;
    while (t >= NT64 - 1 - ti) { t -= NT64 - 1 - ti; ++ti; }
    const int tj = ti + 1 + t;
    const int r0 = ti * MT, c0 = tj * MT;
    const int tid = threadIdx.x;
#pragma unroll
    for (int w = 0; w < 16; ++w) {                 // load (ti,tj) coalesced
        const int idx = w * 256 + tid;
        const int r = idx >> 6, c = idx & 63;
        S[r][c] = H[(size_t)(r0 + r) * N + c0 + c];
    }
    __syncthreads();
#pragma unroll
    for (int w = 0; w < 16; ++w) {                 // store (tj,ti) coalesced
        const int idx = w * 256 + tid;
        const int r = idx >> 6, c = idx & 63;
        H[(size_t)(c0 + r) * N + r0 + c] = S[c][r];
    }
}

extern "C" void kernel_launch(void* const* d_in, const int* in_sizes, int n_in,
                              void* d_out, int out_size, void* d_ws, size_t ws_size,
                              hipStream_t stream) {
    const float* W = (const float*)d_in[0];
    float* H = (float*)d_out;
    (void)in_sizes; (void)n_in; (void)d_ws; (void)ws_size; (void)out_size;

    // zero-init below any result so atomicMax merges cleanly (output is
    // re-poisoned to 0xAA before every timed call -> must zero every call)
    const int n4 = N * N / 4;
    zero_out_kernel<<<(n4 + 255) / 256, 256, 0, stream>>>((float4*)H, n4);
    tropical_gram_kernel<<<dim3(NTRI * SPLIT), dim3(256), 0, stream>>>(W, H);
    mirror_kernel<<<dim3(NMIR), dim3(256), 0, stream>>>(H);
}

// Round 6
// 924.110 us; speedup vs baseline: 2.7815x; 2.7815x over previous
//
#include <hip/hip_runtime.h>
#include <math.h>

// H[i,j] = max_k ( |W[i,k]| + |W[j,k]| ), W: 2048 x 10000 fp32 (values >= 0).
// Max-plus gram: pure VALU (no MFMA). Round 6: revert to round-4 body
// (known 1178 us), fix occupancy correctly:
//  - __launch_bounds__(256,4): VGPR cap 128 >> live set (~76-110) -> NO
//    spill (round 5's (256,5) forced VGPR=48 < acc[64] -> scratch spill
//    storm: WRITE_SIZE 0.26->2.93 GB, 2570 us).
//  - variable K-split: 72 tiles x 8 + 64 tiles x 7 = exactly 1024 blocks
//    = 4 blocks/CU x 256 CU, all co-resident, single scheduling round
//    (no straggler quantization).
//  - canonical-orientation atomics + separate mirror kernel.

constexpr int N  = 2048;
constexpr int K  = 10000;
constexpr int BT = 128;                  // output tile dim
constexpr int BK = 32;                   // k per step
constexpr int NT = N / BT;               // 16
constexpr int NTRI = NT * (NT + 1) / 2;  // 136 upper-tri tiles
constexpr int TILES8 = 72;               // tiles with 8 K-splits
constexpr int BID8 = TILES8 * 8;         // 576 blocks for split-8 tiles
constexpr int CH8 = 1252;                // ceil(10000/8) aligned to 4
constexpr int CH7 = 1432;                // ceil(10000/7) aligned to 4
constexpr int NS8 = 40;                  // ceil(1252/32)
constexpr int NS7 = 45;                  // ceil(1432/32)
// grid = 576 + 64*7 = 1024 blocks

__device__ __forceinline__ float max3f(float a, float b, float c) {
    float d;
    asm("v_max3_f32 %0, %1, %2, %3" : "=v"(d) : "v"(a), "v"(b), "v"(c));
    return d;
}

__global__ void zero_out_kernel(float4* __restrict__ p, int n4) {
    const int i = blockIdx.x * blockDim.x + threadIdx.x;
    if (i < n4) p[i] = make_float4(0.f, 0.f, 0.f, 0.f);
}

__global__ __launch_bounds__(256, 4)
void tropical_gram_kernel(const float* __restrict__ W, float* __restrict__ H) {
    __shared__ float As[BK][BT];   // k-major: As[k][row]
    __shared__ float Bs[BK][BT];

    const int tid = threadIdx.x;

    // ---- block decode: (tile, split-chunk) with variable split count
    const int bid = blockIdx.x;
    int tile, q, kbeg, nstep;
    if (bid < BID8) {
        tile  = bid >> 3;
        q     = bid & 7;
        kbeg  = q * CH8;
        nstep = NS8;
    } else {
        const int r = bid - BID8;
        tile  = TILES8 + r / 7;
        q     = r % 7;
        kbeg  = q * CH7;
        nstep = NS7;
    }
    int t = tile;
    int bi = 0;
    while (t >= NT - bi) { t -= NT - bi; ++bi; }
    const int bj = bi + t;
    const int i0 = bi * BT, j0 = bj * BT;
    const bool diag = (bi == bj);

    // ---- staging mapping: thread stages 16 consecutive k of one row/side
    const int srow = tid & 127;          // row within tile
    const int kh   = tid >> 7;           // 0/1: which 16-k half (wave-uniform)
    const float* rowi = W + (size_t)(i0 + srow) * K + kbeg + kh * 16;
    const float* rowj = W + (size_t)(j0 + srow) * K + kbeg + kh * 16;

    // ---- compute mapping: four 4x4 sub-tiles per thread at (+0,+64)
    const int tx = tid & 15, ty = tid >> 4;
    const int ra = ty * 4, rb = ra + 64;   // row starts
    const int ca = tx * 4, cb = ca + 64;   // col starts

    float acc[8][8];   // m: 0-3 -> ra+m, 4-7 -> rb+(m-4); n likewise ca/cb
#pragma unroll
    for (int m = 0; m < 8; ++m)
#pragma unroll
        for (int n = 0; n < 8; ++n) acc[m][n] = 0.0f;  // all sums >= 0

    // ---- prefetch registers (issue early, LDS-write late)
    float4 va[4], vb[4];
    const float4 z4 = make_float4(0.f, 0.f, 0.f, 0.f);

    auto fetchA = [&](int s) {
#pragma unroll
        for (int qq = 0; qq < 4; ++qq) {
            const int kg = kbeg + kh * 16 + s * BK + qq * 4;  // global k
            va[qq] = (kg < K) ? *reinterpret_cast<const float4*>(rowi + s * BK + qq * 4) : z4;
        }
    };
    auto fetchB = [&](int s) {
#pragma unroll
        for (int qq = 0; qq < 4; ++qq) {
            const int kg = kbeg + kh * 16 + s * BK + qq * 4;
            vb[qq] = (kg < K) ? *reinterpret_cast<const float4*>(rowj + s * BK + qq * 4) : z4;
        }
    };

    fetchA(0);
    if (!diag) fetchB(0);

    // diagonal blocks read B fragments from As (half the staging)
    const float (*Bsrc)[BT] = diag ? As : Bs;

    for (int s = 0; s < nstep; ++s) {
        __syncthreads();                 // previous compute done with LDS
        // transposed LDS write: bank = srow%32 across lanes -> 2-way (free)
#pragma unroll
        for (int qq = 0; qq < 4; ++qq) {
            const int kb = kh * 16 + qq * 4;
            As[kb + 0][srow] = fabsf(va[qq].x);
            As[kb + 1][srow] = fabsf(va[qq].y);
            As[kb + 2][srow] = fabsf(va[qq].z);
            As[kb + 3][srow] = fabsf(va[qq].w);
        }
        if (!diag) {
#pragma unroll
            for (int qq = 0; qq < 4; ++qq) {
                const int kb = kh * 16 + qq * 4;
                Bs[kb + 0][srow] = fabsf(vb[qq].x);
                Bs[kb + 1][srow] = fabsf(vb[qq].y);
                Bs[kb + 2][srow] = fabsf(vb[qq].z);
                Bs[kb + 3][srow] = fabsf(vb[qq].w);
            }
        }
        if (s + 1 < nstep) {             // issue next-step loads under compute
            fetchA(s + 1);
            if (!diag) fetchB(s + 1);
        }
        __syncthreads();                 // LDS tile ready

#pragma unroll 2
        for (int kk = 0; kk < BK; kk += 2) {
            // all reads stride-16B across lanes -> <=2-way bank aliasing
            const float4 A0a = *reinterpret_cast<const float4*>(&As[kk][ra]);
            const float4 A0b = *reinterpret_cast<const float4*>(&As[kk][rb]);
            const float4 A1a = *reinterpret_cast<const float4*>(&As[kk + 1][ra]);
            const float4 A1b = *reinterpret_cast<const float4*>(&As[kk + 1][rb]);
            const float4 B0a = *reinterpret_cast<const float4*>(&Bsrc[kk][ca]);
            const float4 B0b = *reinterpret_cast<const float4*>(&Bsrc[kk][cb]);
            const float4 B1a = *reinterpret_cast<const float4*>(&Bsrc[kk + 1][ca]);
            const float4 B1b = *reinterpret_cast<const float4*>(&Bsrc[kk + 1][cb]);
            const float a0[8] = {A0a.x, A0a.y, A0a.z, A0a.w, A0b.x, A0b.y, A0b.z, A0b.w};
            const float a1[8] = {A1a.x, A1a.y, A1a.z, A1a.w, A1b.x, A1b.y, A1b.z, A1b.w};
            const float b0[8] = {B0a.x, B0a.y, B0a.z, B0a.w, B0b.x, B0b.y, B0b.z, B0b.w};
            const float b1[8] = {B1a.x, B1a.y, B1a.z, B1a.w, B1b.x, B1b.y, B1b.z, B1b.w};
#pragma unroll
            for (int m = 0; m < 8; ++m) {
#pragma unroll
                for (int n = 0; n < 8; ++n) {
                    const float t0 = a0[m] + b0[n];
                    const float t1 = a1[m] + b1[n];
                    acc[m][n] = max3f(acc[m][n], t0, t1);
                }
            }
        }
    }

    // ---- epilogue: canonical orientation only; int-bitcast atomicMax merges
    // the K-splits (all values >= 0 -> float order == int order)
    int* Hi = (int*)H;
#pragma unroll
    for (int m = 0; m < 8; ++m) {
        const int r = (m < 4) ? (ra + m) : (rb + m - 4);
#pragma unroll
        for (int n = 0; n < 8; ++n) {
            const int c = (n < 4) ? (ca + n) : (cb + n - 4);
            atomicMax(&Hi[(size_t)(i0 + r) * N + j0 + c], __float_as_int(acc[m][n]));
        }
    }
}

// fill strictly-lower 64-tiles from the upper triangle (H[j][i] = H[i][j]).
// diag-128 tiles were written fully by the gram kernel; re-copying the
// intra-diagonal 64-tile pairs is idempotent (same values).
constexpr int MT  = 64;
constexpr int NT64 = N / MT;                       // 32
constexpr int NMIR = NT64 * (NT64 - 1) / 2;        // 496 strict pairs

__global__ __launch_bounds__(256)
void mirror_kernel(float* __restrict__ H) {
    __shared__ float S[MT][MT + 1];                // +1 pad: conflict-free transpose
    int t = blockIdx.x;
    int ti = 0;
    while (t >= NT64 - 1 - ti) { t -= NT64 - 1 - ti; ++ti; }
    const int tj = ti + 1 + t;
    const int r0 = ti * MT, c0 = tj * MT;
    const int tid = threadIdx.x;
#pragma unroll
    for (int w = 0; w < 16; ++w) {                 // load (ti,tj) coalesced
        const int idx = w * 256 + tid;
        const int r = idx >> 6, c = idx & 63;
        S[r][c] = H[(size_t)(r0 + r) * N + c0 + c];
    }
    __syncthreads();
#pragma unroll
    for (int w = 0; w < 16; ++w) {                 // store (tj,ti) coalesced
        const int idx = w * 256 + tid;
        const int r = idx >> 6, c = idx & 63;
        H[(size_t)(c0 + r) * N + r0 + c] = S[c][r];
    }
}

extern "C" void kernel_launch(void* const* d_in, const int* in_sizes, int n_in,
                              void* d_out, int out_size, void* d_ws, size_t ws_size,
                              hipStream_t stream) {
    const float* W = (const float*)d_in[0];
    float* H = (float*)d_out;
    (void)in_sizes; (void)n_in; (void)d_ws; (void)ws_size; (void)out_size;

    // zero-init below any result so atomicMax merges cleanly (output is
    // re-poisoned to 0xAA before every timed call -> must zero every call)
    const int n4 = N * N / 4;
    zero_out_kernel<<<(n4 + 255) / 256, 256, 0, stream>>>((float4*)H, n4);
    tropical_gram_kernel<<<dim3(1024), dim3(256), 0, stream>>>(W, H);
    mirror_kernel<<<dim3(NMIR), dim3(256), 0, stream>>>(H);
}